// Round 1
// baseline (381.739 us; speedup 1.0000x reference)
//
#include <hip/hip_runtime.h>
#include <hip/hip_bf16.h>

typedef __attribute__((ext_vector_type(4))) float f32x4;
typedef __attribute__((ext_vector_type(8))) short short8;
typedef __attribute__((ext_vector_type(8))) __bf16 bf16x8;

#define NDIM 172
#define EDIM 172
#define TDIM 100
#define KCAT 444   // 172+172+100
#define KPAD 448
#define QDIM 272   // 172+100
#define ODIM 128
#define ZDIM 256
#define NNBR 32
#define BPB 4      // batch rows per block
#define MROWS 128  // BPB*32
#define KSTEP 64
#define LN_EPS 1e-5f

__device__ __forceinline__ unsigned short f2bf(float f) {
    unsigned u = __builtin_bit_cast(unsigned, f);
    u += 0x7fffu + ((u >> 16) & 1u);
    return (unsigned short)(u >> 16);
}
__device__ __forceinline__ float bf2f(unsigned short h) {
    unsigned u = ((unsigned)h) << 16;
    return __builtin_bit_cast(float, u);
}

// Pack Wkv [256][444] fp32 -> bf16 [256][448] (zero-padded K)
__global__ void prep_wkv(const float* __restrict__ Wkv, unsigned short* __restrict__ wpack) {
    int idx = blockIdx.x * 256 + threadIdx.x;
    if (idx >= 256 * KPAD) return;
    int row = idx / KPAD, k = idx - row * KPAD;
    float v = (k < KCAT) ? Wkv[row * KCAT + k] : 0.f;
    wpack[idx] = f2bf(v);
}

__global__ __launch_bounds__(512) void ta_fused(
    const float* __restrict__ node_feat, const float* __restrict__ time_feat,
    const float* __restrict__ edge_feat, const float* __restrict__ nbr_node,
    const float* __restrict__ nbr_time, const int* __restrict__ nbr_mask,
    const float* __restrict__ Wq, const float* __restrict__ bq,
    const unsigned short* __restrict__ wpack, const float* __restrict__ bkv,
    const float* __restrict__ Wo, const float* __restrict__ bo,
    const float* __restrict__ gamma, const float* __restrict__ beta,
    float* __restrict__ out)
{
    // union region: GEMM staging (A:16K @0, W:32K @16K) then Z bf16 [128][256] (64K)
    __shared__ __align__(16) unsigned char smem[65536];
    __shared__ float qfeat[BPB][QDIM];
    __shared__ float qres[BPB][ODIM];
    __shared__ float Pband[BPB][2][NNBR];
    __shared__ float Obuf[BPB][ODIM];
    __shared__ float red[8][2];

    const int tid  = threadIdx.x;
    const int lane = tid & 63;
    const int wid  = tid >> 6;
    const int b0   = blockIdx.x * BPB;

    unsigned short* Z_lds = (unsigned short*)smem;  // [128][256] after GEMM

    // ---- stage Q features (concat node||time) for the 4 batch rows
    for (int g = tid; g < BPB * QDIM; g += 512) {
        int b = g / QDIM, k = g - b * QDIM;
        qfeat[b][k] = (k < NDIM) ? node_feat[(long)(b0 + b) * NDIM + k]
                                 : time_feat[(long)(b0 + b) * TDIM + (k - NDIM)];
    }

    // ---- GEMM: Z[128][256] = A[128][448] * Wkv_packed[256][448]^T
    f32x4 acc[4][4];
    #pragma unroll
    for (int m = 0; m < 4; m++)
        #pragma unroll
        for (int n = 0; n < 4; n++) acc[m][n] = (f32x4){0.f, 0.f, 0.f, 0.f};

    const int wm = wid >> 2;   // 0..1 : 64-row band
    const int wn = wid & 3;    // 0..3 : 64-col band

    for (int ks = 0; ks < KPAD / KSTEP; ks++) {
        const int k0 = ks * KSTEP;
        __syncthreads();
        // stage A tile: 128 rows x 64 k, fp32 gather (3 sources) -> bf16, swizzled
        #pragma unroll
        for (int i = 0; i < 4; i++) {
            int g = i * 512 + tid;            // [0, 2048)
            int row = g >> 4, grp = g & 15;   // 16 float4-groups per row
            int k = k0 + grp * 4;
            int bl = row >> 5, n = row & 31;
            long rg = (long)(b0 + bl) * NNBR + n;
            float4 v;
            if (k < NDIM)             v = *(const float4*)(nbr_node  + rg * NDIM + k);
            else if (k < NDIM + EDIM) v = *(const float4*)(edge_feat + rg * EDIM + (k - NDIM));
            else if (k < KCAT)        v = *(const float4*)(nbr_time  + rg * TDIM + (k - NDIM - EDIM));
            else                      v = make_float4(0.f, 0.f, 0.f, 0.f);
            ushort4 h = make_ushort4(f2bf(v.x), f2bf(v.y), f2bf(v.z), f2bf(v.w));
            int byte = (row * 128 + grp * 8) ^ ((row & 7) << 4);
            *(ushort4*)(smem + byte) = h;
        }
        // stage W tile: 256 rows x 64 bf16 (pre-packed), swizzled
        #pragma unroll
        for (int i = 0; i < 4; i++) {
            int g = i * 512 + tid;            // [0, 2048)
            int row = g >> 3, f8 = g & 7;     // 8 x 16B chunks per row (128B)
            uint4 v = *(const uint4*)(wpack + (long)row * KPAD + k0 + f8 * 8);
            int byte = (row * 128 + f8 * 16) ^ ((row & 7) << 4);
            *(uint4*)(smem + 16384 + byte) = v;
        }
        __syncthreads();
        // compute: two K=32 halves
        #pragma unroll
        for (int kk = 0; kk < 2; kk++) {
            const int kb = kk * 64 + (lane >> 4) * 16;  // byte offset in row
            bf16x8 af[4], bfr[4];
            #pragma unroll
            for (int m = 0; m < 4; m++) {
                int row = wm * 64 + m * 16 + (lane & 15);
                int byte = (row * 128 + kb) ^ ((row & 7) << 4);
                af[m] = __builtin_bit_cast(bf16x8, *(const short8*)(smem + byte));
            }
            #pragma unroll
            for (int n = 0; n < 4; n++) {
                int row = wn * 64 + n * 16 + (lane & 15);
                int byte = (row * 128 + kb) ^ ((row & 7) << 4);
                bfr[n] = __builtin_bit_cast(bf16x8, *(const short8*)(smem + 16384 + byte));
            }
            #pragma unroll
            for (int m = 0; m < 4; m++)
                #pragma unroll
                for (int n = 0; n < 4; n++)
                    acc[m][n] = __builtin_amdgcn_mfma_f32_16x16x32_bf16(af[m], bfr[n], acc[m][n], 0, 0, 0);
        }
    }

    __syncthreads();
    // ---- dump Z (+bkv) to LDS as bf16, C/D layout: col=lane&15, row=(lane>>4)*4+j
    #pragma unroll
    for (int n = 0; n < 4; n++) {
        int col = wn * 64 + n * 16 + (lane & 15);
        float bk = bkv[col];
        #pragma unroll
        for (int m = 0; m < 4; m++) {
            #pragma unroll
            for (int j = 0; j < 4; j++) {
                int row = wm * 64 + m * 16 + (lane >> 4) * 4 + j;
                Z_lds[row * ZDIM + col] = f2bf(acc[m][n][j] + bk);
            }
        }
    }

    // ---- Q projection: [4,272] @ Wq[128,272]^T + bq  (fp32 VALU, tiny)
    {
        int b = tid >> 7, c = tid & 127;
        float s = bq[c];
        const float* wr = Wq + c * QDIM;
        const float* qf = qfeat[b];
        #pragma unroll 4
        for (int k = 0; k < QDIM; k++) s += wr[k] * qf[k];
        qres[b][c] = s;
    }
    __syncthreads();

    // ---- scores + softmax: wave w -> (b=w>>1, h=w&1); lane pair per position n2
    {
        int bl = wid >> 1, h = wid & 1;
        int n2 = lane >> 1, half = lane & 1;
        int np = h * 16 + (n2 >> 1);                  // Z row (mixed reshape)
        int cb = (n2 & 1) * 64 + half * 32;           // Z col base (K part)
        const unsigned short* zr = Z_lds + (bl * NNBR + np) * ZDIM + cb;
        const float* q = &qres[bl][h * 64 + half * 32];
        float s = 0.f;
        #pragma unroll 8
        for (int d = 0; d < 32; d++) s += q[d] * bf2f(zr[d]);
        s += __shfl_xor(s, 1);
        s *= 0.125f;  // HEAD_DIM^-0.5
        if (nbr_mask[(long)(b0 + bl) * NNBR + n2] == 0) s = -1e10f;
        float mx = s;
        #pragma unroll
        for (int off = 1; off < 64; off <<= 1) mx = fmaxf(mx, __shfl_xor(mx, off));
        float e = __expf(s - mx);
        float sum = e;
        #pragma unroll
        for (int off = 1; off < 64; off <<= 1) sum += __shfl_xor(sum, off);
        float p = e * 2.f / sum;   // each n2 counted twice in sum
        if (half == 0) Pband[bl][h][n2] = p;
    }
    __syncthreads();

    // ---- O = P @ V : one thread per (b, h*64+d)
    {
        int b = tid >> 7, c = tid & 127, h = c >> 6, d = c & 63;
        const float* P = Pband[b][h];
        float s = 0.f;
        #pragma unroll
        for (int n2 = 0; n2 < NNBR; n2++) {
            int np = h * 16 + (n2 >> 1);
            int col = ODIM + (n2 & 1) * 64 + d;       // V part
            s += P[n2] * bf2f(Z_lds[(b * NNBR + np) * ZDIM + col]);
        }
        Obuf[b][c] = s;
    }
    __syncthreads();

    // ---- out proj + LayerNorm
    {
        int b = tid >> 7, c = tid & 127;
        float s = bo[c];
        const float* wr = Wo + c * ODIM;
        const float* ob = Obuf[b];
        #pragma unroll 8
        for (int k = 0; k < ODIM; k++) s += wr[k] * ob[k];
        float s1 = s, s2 = s * s;
        #pragma unroll
        for (int off = 1; off < 64; off <<= 1) {
            s1 += __shfl_xor(s1, off);
            s2 += __shfl_xor(s2, off);
        }
        if (lane == 0) { red[wid][0] = s1; red[wid][1] = s2; }
        __syncthreads();
        float t1 = red[b * 2][0] + red[b * 2 + 1][0];
        float t2 = red[b * 2][1] + red[b * 2 + 1][1];
        float mu  = t1 * (1.f / 128.f);
        float var = t2 * (1.f / 128.f) - mu * mu;
        float inv = rsqrtf(var + LN_EPS);
        out[(long)(b0 + b) * ODIM + c] = (s - mu) * inv * gamma[c] + beta[c];
    }
}

extern "C" void kernel_launch(void* const* d_in, const int* in_sizes, int n_in,
                              void* d_out, int out_size, void* d_ws, size_t ws_size,
                              hipStream_t stream) {
    const float* node_feat = (const float*)d_in[0];
    const float* time_feat = (const float*)d_in[1];
    const float* edge_feat = (const float*)d_in[2];
    const float* nbr_node  = (const float*)d_in[3];
    const float* nbr_time  = (const float*)d_in[4];
    const int*   nbr_mask  = (const int*)d_in[5];
    const float* Wq   = (const float*)d_in[6];
    const float* bq   = (const float*)d_in[7];
    const float* Wkv  = (const float*)d_in[8];
    const float* bkv  = (const float*)d_in[9];
    const float* Wo   = (const float*)d_in[10];
    const float* bo   = (const float*)d_in[11];
    const float* gma  = (const float*)d_in[12];
    const float* bta  = (const float*)d_in[13];
    float* out = (float*)d_out;
    unsigned short* wpack = (unsigned short*)d_ws;

    const int B = in_sizes[0] / NDIM;  // 8192

    prep_wkv<<<dim3((256 * KPAD + 255) / 256), dim3(256), 0, stream>>>(Wkv, wpack);
    ta_fused<<<dim3(B / BPB), dim3(512), 0, stream>>>(
        node_feat, time_feat, edge_feat, nbr_node, nbr_time, nbr_mask,
        Wq, bq, wpack, bkv, Wo, bo, gma, bta, out);
}